// Round 3
// baseline (19535.741 us; speedup 1.0000x reference)
//
#include <hip/hip_runtime.h>

// ---------------------------------------------------------------------------
// MutualRec forward: 5x GATv2 + ChebConv(k=3) + mutualistic MLP + edge dots
// R2: ILP-4 row GEMMs; single-pass GAT edge kernel (no max-sub softmax);
//     alpha-normalization folded into consuming GEMMs; grid-stride caps.
// ---------------------------------------------------------------------------

#define LRELU_SLOPE 0.2f
#define GEMM_BLOCKS 1024
#define EDGE_BLOCKS 2048

// ---- Y[N,64] = norm(X) @ W + b ; norm = row/den[row] if den!=null ----
__global__ void gemm64_k(const float* __restrict__ X, const float* __restrict__ W,
                         const float* __restrict__ b, const float* __restrict__ den,
                         float* __restrict__ Y, int N) {
  __shared__ float Ws[64 * 64];
  for (int i = threadIdx.x; i < 64 * 64; i += blockDim.x) Ws[i] = W[i];
  __syncthreads();
  const int lane = threadIdx.x & 63;
  const int wid = (blockIdx.x * blockDim.x + threadIdx.x) >> 6;
  const int nw = (gridDim.x * blockDim.x) >> 6;
  const float bj = b[lane];
  for (int r0 = wid * 4; r0 < N; r0 += nw * 4) {
    float x0 = X[(size_t)r0 * 64 + lane];
    float x1 = (r0 + 1 < N) ? X[(size_t)(r0 + 1) * 64 + lane] : 0.0f;
    float x2 = (r0 + 2 < N) ? X[(size_t)(r0 + 2) * 64 + lane] : 0.0f;
    float x3 = (r0 + 3 < N) ? X[(size_t)(r0 + 3) * 64 + lane] : 0.0f;
    if (den) {
      float d0 = den[r0];
      float d1 = (r0 + 1 < N) ? den[r0 + 1] : 1.0f;
      float d2 = (r0 + 2 < N) ? den[r0 + 2] : 1.0f;
      float d3 = (r0 + 3 < N) ? den[r0 + 3] : 1.0f;
      x0 = d0 > 0.0f ? x0 * (1.0f / d0) : 0.0f;
      x1 = d1 > 0.0f ? x1 * (1.0f / d1) : 0.0f;
      x2 = d2 > 0.0f ? x2 * (1.0f / d2) : 0.0f;
      x3 = d3 > 0.0f ? x3 * (1.0f / d3) : 0.0f;
    }
    float a0 = bj, a1 = bj, a2 = bj, a3 = bj;
#pragma unroll
    for (int k = 0; k < 64; ++k) {
      const float w = Ws[k * 64 + lane];
      a0 = fmaf(__shfl(x0, k, 64), w, a0);
      a1 = fmaf(__shfl(x1, k, 64), w, a1);
      a2 = fmaf(__shfl(x2, k, 64), w, a2);
      a3 = fmaf(__shfl(x3, k, 64), w, a3);
    }
    Y[(size_t)r0 * 64 + lane] = a0;
    if (r0 + 1 < N) Y[(size_t)(r0 + 1) * 64 + lane] = a1;
    if (r0 + 2 < N) Y[(size_t)(r0 + 2) * 64 + lane] = a2;
    if (r0 + 3 < N) Y[(size_t)(r0 + 3) * 64 + lane] = a3;
  }
}

// ---- Y[N,64] = concat(norm(A), norm(B)) @ W[128,64] + b ----
__global__ void gemm128_k(const float* __restrict__ A, const float* __restrict__ Bm,
                          const float* __restrict__ W, const float* __restrict__ b,
                          const float* __restrict__ denA, const float* __restrict__ denB,
                          float* __restrict__ Y, int N) {
  __shared__ float Ws[128 * 64];
  for (int i = threadIdx.x; i < 128 * 64; i += blockDim.x) Ws[i] = W[i];
  __syncthreads();
  const int lane = threadIdx.x & 63;
  const int wid = (blockIdx.x * blockDim.x + threadIdx.x) >> 6;
  const int nw = (gridDim.x * blockDim.x) >> 6;
  const float bj = b[lane];
  for (int r0 = wid * 4; r0 < N; r0 += nw * 4) {
    float a0 = A[(size_t)r0 * 64 + lane];
    float a1 = (r0 + 1 < N) ? A[(size_t)(r0 + 1) * 64 + lane] : 0.0f;
    float a2 = (r0 + 2 < N) ? A[(size_t)(r0 + 2) * 64 + lane] : 0.0f;
    float a3 = (r0 + 3 < N) ? A[(size_t)(r0 + 3) * 64 + lane] : 0.0f;
    float c0 = Bm[(size_t)r0 * 64 + lane];
    float c1 = (r0 + 1 < N) ? Bm[(size_t)(r0 + 1) * 64 + lane] : 0.0f;
    float c2 = (r0 + 2 < N) ? Bm[(size_t)(r0 + 2) * 64 + lane] : 0.0f;
    float c3 = (r0 + 3 < N) ? Bm[(size_t)(r0 + 3) * 64 + lane] : 0.0f;
    if (denA) {
      float d0 = denA[r0];
      float d1 = (r0 + 1 < N) ? denA[r0 + 1] : 1.0f;
      float d2 = (r0 + 2 < N) ? denA[r0 + 2] : 1.0f;
      float d3 = (r0 + 3 < N) ? denA[r0 + 3] : 1.0f;
      a0 = d0 > 0.0f ? a0 * (1.0f / d0) : 0.0f;
      a1 = d1 > 0.0f ? a1 * (1.0f / d1) : 0.0f;
      a2 = d2 > 0.0f ? a2 * (1.0f / d2) : 0.0f;
      a3 = d3 > 0.0f ? a3 * (1.0f / d3) : 0.0f;
    }
    if (denB) {
      float d0 = denB[r0];
      float d1 = (r0 + 1 < N) ? denB[r0 + 1] : 1.0f;
      float d2 = (r0 + 2 < N) ? denB[r0 + 2] : 1.0f;
      float d3 = (r0 + 3 < N) ? denB[r0 + 3] : 1.0f;
      c0 = d0 > 0.0f ? c0 * (1.0f / d0) : 0.0f;
      c1 = d1 > 0.0f ? c1 * (1.0f / d1) : 0.0f;
      c2 = d2 > 0.0f ? c2 * (1.0f / d2) : 0.0f;
      c3 = d3 > 0.0f ? c3 * (1.0f / d3) : 0.0f;
    }
    float y0 = bj, y1 = bj, y2 = bj, y3 = bj;
#pragma unroll
    for (int k = 0; k < 64; ++k) {
      const float w = Ws[k * 64 + lane];
      y0 = fmaf(__shfl(a0, k, 64), w, y0);
      y1 = fmaf(__shfl(a1, k, 64), w, y1);
      y2 = fmaf(__shfl(a2, k, 64), w, y2);
      y3 = fmaf(__shfl(a3, k, 64), w, y3);
    }
#pragma unroll
    for (int k = 0; k < 64; ++k) {
      const float w = Ws[(64 + k) * 64 + lane];
      y0 = fmaf(__shfl(c0, k, 64), w, y0);
      y1 = fmaf(__shfl(c1, k, 64), w, y1);
      y2 = fmaf(__shfl(c2, k, 64), w, y2);
      y3 = fmaf(__shfl(c3, k, 64), w, y3);
    }
    Y[(size_t)r0 * 64 + lane] = y0;
    if (r0 + 1 < N) Y[(size_t)(r0 + 1) * 64 + lane] = y1;
    if (r0 + 2 < N) Y[(size_t)(r0 + 2) * 64 + lane] = y2;
    if (r0 + 3 < N) Y[(size_t)(r0 + 3) * 64 + lane] = y3;
  }
}

// ---- rst = T0@W0 + T1@W1 + T2@W2 + b (fused Cheb combine, ILP-4) ----
__global__ void cheb3_k(const float* __restrict__ T0, const float* __restrict__ T1,
                        const float* __restrict__ T2, const float* __restrict__ W3,
                        const float* __restrict__ b, float* __restrict__ Y, int N) {
  __shared__ float Ws[3 * 64 * 64];
  for (int i = threadIdx.x; i < 3 * 64 * 64; i += blockDim.x) Ws[i] = W3[i];
  __syncthreads();
  const int lane = threadIdx.x & 63;
  const int wid = (blockIdx.x * blockDim.x + threadIdx.x) >> 6;
  const int nw = (gridDim.x * blockDim.x) >> 6;
  const float bj = b[lane];
  for (int r0 = wid * 4; r0 < N; r0 += nw * 4) {
    float p0 = T0[(size_t)r0 * 64 + lane];
    float p1 = (r0 + 1 < N) ? T0[(size_t)(r0 + 1) * 64 + lane] : 0.0f;
    float p2 = (r0 + 2 < N) ? T0[(size_t)(r0 + 2) * 64 + lane] : 0.0f;
    float p3 = (r0 + 3 < N) ? T0[(size_t)(r0 + 3) * 64 + lane] : 0.0f;
    float q0 = T1[(size_t)r0 * 64 + lane];
    float q1 = (r0 + 1 < N) ? T1[(size_t)(r0 + 1) * 64 + lane] : 0.0f;
    float q2 = (r0 + 2 < N) ? T1[(size_t)(r0 + 2) * 64 + lane] : 0.0f;
    float q3 = (r0 + 3 < N) ? T1[(size_t)(r0 + 3) * 64 + lane] : 0.0f;
    float s0 = T2[(size_t)r0 * 64 + lane];
    float s1 = (r0 + 1 < N) ? T2[(size_t)(r0 + 1) * 64 + lane] : 0.0f;
    float s2 = (r0 + 2 < N) ? T2[(size_t)(r0 + 2) * 64 + lane] : 0.0f;
    float s3 = (r0 + 3 < N) ? T2[(size_t)(r0 + 3) * 64 + lane] : 0.0f;
    float y0 = bj, y1 = bj, y2 = bj, y3 = bj;
#pragma unroll
    for (int k = 0; k < 64; ++k) {
      float w = Ws[k * 64 + lane];
      y0 = fmaf(__shfl(p0, k, 64), w, y0);
      y1 = fmaf(__shfl(p1, k, 64), w, y1);
      y2 = fmaf(__shfl(p2, k, 64), w, y2);
      y3 = fmaf(__shfl(p3, k, 64), w, y3);
      w = Ws[4096 + k * 64 + lane];
      y0 = fmaf(__shfl(q0, k, 64), w, y0);
      y1 = fmaf(__shfl(q1, k, 64), w, y1);
      y2 = fmaf(__shfl(q2, k, 64), w, y2);
      y3 = fmaf(__shfl(q3, k, 64), w, y3);
      w = Ws[8192 + k * 64 + lane];
      y0 = fmaf(__shfl(s0, k, 64), w, y0);
      y1 = fmaf(__shfl(s1, k, 64), w, y1);
      y2 = fmaf(__shfl(s2, k, 64), w, y2);
      y3 = fmaf(__shfl(s3, k, 64), w, y3);
    }
    Y[(size_t)r0 * 64 + lane] = y0;
    if (r0 + 1 < N) Y[(size_t)(r0 + 1) * 64 + lane] = y1;
    if (r0 + 2 < N) Y[(size_t)(r0 + 2) * 64 + lane] = y2;
    if (r0 + 3 < N) Y[(size_t)(r0 + 3) * 64 + lane] = y3;
  }
}

// ---- single-pass GATv2 edge kernel: score->exp->den/out atomics ----
// out[d] accumulates exp(s_e)*fs[src_e]; den[d] accumulates exp(s_e).
// Normalization happens in the consuming GEMM (division by den).
__global__ void gat_edge_k(const float* __restrict__ fs, const float* __restrict__ fd,
                           const float* __restrict__ attn, const int* __restrict__ src,
                           const int* __restrict__ dst, float* __restrict__ den,
                           float* __restrict__ out, int E) {
  const int lane = threadIdx.x & 63;
  const int wid = (blockIdx.x * blockDim.x + threadIdx.x) >> 6;
  const int nw = (gridDim.x * blockDim.x) >> 6;
  const float aw = attn[lane];
  for (int e = wid; e < E; e += nw) {
    const int s = src[e], d = dst[e];
    const float fsv = fs[(size_t)s * 64 + lane];
    float v = fsv + fd[(size_t)d * 64 + lane];
    v = v > 0.0f ? v : LRELU_SLOPE * v;
    float p = v * aw;
#pragma unroll
    for (int o = 32; o; o >>= 1) p += __shfl_xor(p, o, 64);
    const float ex = __expf(p);
    if (lane == 0) atomicAdd(den + d, ex);
    atomicAdd(out + (size_t)d * 64 + lane, ex * fsv);
  }
}

// ---- Cheb: in-degree count ----
__global__ void indeg_k(const int* __restrict__ dst, float* __restrict__ deg, int E) {
  const int e = blockIdx.x * blockDim.x + threadIdx.x;
  if (e < E) atomicAdd(deg + dst[e], 1.0f);
}
__global__ void dinv_k(float* __restrict__ deg, int N) {
  const int i = blockIdx.x * blockDim.x + threadIdx.x;
  if (i < N) deg[i] = rsqrtf(fmaxf(deg[i], 1.0f));
}

// ---- Cheb: h[dst] += x[src]*dinv[src] (wave per edge, grid-stride) ----
__global__ void ahat_k(const float* __restrict__ x, const float* __restrict__ dinv,
                       const int* __restrict__ src, const int* __restrict__ dst,
                       float* __restrict__ h, int E) {
  const int lane = threadIdx.x & 63;
  const int wid = (blockIdx.x * blockDim.x + threadIdx.x) >> 6;
  const int nw = (gridDim.x * blockDim.x) >> 6;
  for (int e = wid; e < E; e += nw) {
    const int s = src[e], d = dst[e];
    atomicAdd(h + (size_t)d * 64 + lane, x[(size_t)s * 64 + lane] * dinv[s]);
  }
}

// ---- T1 = -re*(dinv*h) + (re-1)*T0  (float4) ----
__global__ void t1_k(const float4* __restrict__ h, const float4* __restrict__ T0,
                     const float* __restrict__ dinv, const float* __restrict__ lam,
                     float4* __restrict__ T1, int n4) {
  const float re = 2.0f / lam[0];
  const int stride = gridDim.x * blockDim.x;
  for (int i = blockIdx.x * blockDim.x + threadIdx.x; i < n4; i += stride) {
    const float sc = dinv[i >> 4];
    const float4 hv = h[i], t0 = T0[i];
    float4 r;
    r.x = -re * (sc * hv.x) + (re - 1.0f) * t0.x;
    r.y = -re * (sc * hv.y) + (re - 1.0f) * t0.y;
    r.z = -re * (sc * hv.z) + (re - 1.0f) * t0.z;
    r.w = -re * (sc * hv.w) + (re - 1.0f) * t0.w;
    T1[i] = r;
  }
}

// ---- T2 = -2re*(dinv*h2) + 2(re-1)*T1 - T0  (float4) ----
__global__ void t2_k(const float4* __restrict__ h2, const float4* __restrict__ T1,
                     const float4* __restrict__ T0, const float* __restrict__ dinv,
                     const float* __restrict__ lam, float4* __restrict__ T2, int n4) {
  const float re = 2.0f / lam[0];
  const int stride = gridDim.x * blockDim.x;
  for (int i = blockIdx.x * blockDim.x + threadIdx.x; i < n4; i += stride) {
    const float sc = dinv[i >> 4];
    const float4 hv = h2[i], t1 = T1[i], t0 = T0[i];
    float4 r;
    r.x = -2.0f * re * (sc * hv.x) + 2.0f * (re - 1.0f) * t1.x - t0.x;
    r.y = -2.0f * re * (sc * hv.y) + 2.0f * (re - 1.0f) * t1.y - t0.y;
    r.z = -2.0f * re * (sc * hv.z) + 2.0f * (re - 1.0f) * t1.z - t0.z;
    r.w = -2.0f * re * (sc * hv.w) + 2.0f * (re - 1.0f) * t1.w - t0.w;
    T2[i] = r;
  }
}

// ---- mutualistic: mP = (p*s)*softmax(p), mS = (p*s)*softmax(s) (wave/row) ----
__global__ void mut_k(const float* __restrict__ hP, const float* __restrict__ hS,
                      float* __restrict__ mP, float* __restrict__ mS, int N) {
  const int lane = threadIdx.x & 63;
  const int u = (blockIdx.x * blockDim.x + threadIdx.x) >> 6;
  if (u >= N) return;
  const float p = hP[(size_t)u * 64 + lane];
  const float s = hS[(size_t)u * 64 + lane];
  const float m = p * s;
  float mxp = p, mxs = s;
#pragma unroll
  for (int o = 32; o; o >>= 1) {
    mxp = fmaxf(mxp, __shfl_xor(mxp, o, 64));
    mxs = fmaxf(mxs, __shfl_xor(mxs, o, 64));
  }
  float ep = __expf(p - mxp);
  float es = __expf(s - mxs);
  float sp = ep, ss = es;
#pragma unroll
  for (int o = 32; o; o >>= 1) {
    sp += __shfl_xor(sp, o, 64);
    ss += __shfl_xor(ss, o, 64);
  }
  mP[(size_t)u * 64 + lane] = m * (ep / sp);
  mS[(size_t)u * 64 + lane] = m * (es / ss);
}

// ---- edge dot: out[e] = <A[src[e]], B[dst[e]]> (wave per edge, ILP-2) ----
__global__ void dot_k(const float* __restrict__ A, const float* __restrict__ Bm,
                      const int* __restrict__ src, const int* __restrict__ dst,
                      float* __restrict__ out, int E) {
  const int lane = threadIdx.x & 63;
  const int wid = (blockIdx.x * blockDim.x + threadIdx.x) >> 6;
  const int nw = (gridDim.x * blockDim.x) >> 6;
  for (int e0 = wid * 2; e0 < E; e0 += nw * 2) {
    const bool has1 = (e0 + 1 < E);
    const int s0 = src[e0], d0 = dst[e0];
    const int s1 = has1 ? src[e0 + 1] : s0;
    const int d1 = has1 ? dst[e0 + 1] : d0;
    float p0 = A[(size_t)s0 * 64 + lane] * Bm[(size_t)d0 * 64 + lane];
    float p1 = A[(size_t)s1 * 64 + lane] * Bm[(size_t)d1 * 64 + lane];
#pragma unroll
    for (int o = 32; o; o >>= 1) {
      p0 += __shfl_xor(p0, o, 64);
      p1 += __shfl_xor(p1, o, 64);
    }
    if (lane == 0) {
      out[e0] = p0;
      if (has1) out[e0 + 1] = p1;
    }
  }
}

// ---------------------------------------------------------------------------

static void run_gat(const float* hsrc, int Ns, const float* dsrc_den,
                    const float* hdst, int Nd, const float* ddst_den,
                    const float* Wsrc, const float* bsrc,
                    const float* Wdst, const float* bdst, const float* attn,
                    const int* src, const int* dst, int E,
                    float* fs, float* fd, float* out, float* den,
                    hipStream_t stream) {
  gemm64_k<<<GEMM_BLOCKS, 256, 0, stream>>>(hsrc, Wsrc, bsrc, dsrc_den, fs, Ns);
  gemm64_k<<<GEMM_BLOCKS, 256, 0, stream>>>(hdst, Wdst, bdst, ddst_den, fd, Nd);
  hipMemsetAsync(den, 0, (size_t)Nd * 4, stream);
  hipMemsetAsync(out, 0, (size_t)Nd * 64 * 4, stream);
  gat_edge_k<<<EDGE_BLOCKS, 256, 0, stream>>>(fs, fd, attn, src, dst, den, out, E);
}

extern "C" void kernel_launch(void* const* d_in, const int* in_sizes, int n_in,
                              void* d_out, int out_size, void* d_ws, size_t ws_size,
                              hipStream_t stream) {
  const float* user_emb = (const float*)d_in[0];
  const float* item_emb = (const float*)d_in[1];
  const int* rate_src = (const int*)d_in[2];
  const int* rate_dst = (const int*)d_in[3];
  const int* link_src = (const int*)d_in[4];
  const int* link_dst = (const int*)d_in[5];
  const int* neg_rate_src = (const int*)d_in[6];
  const int* neg_rate_dst = (const int*)d_in[7];
  const int* neg_link_src = (const int*)d_in[8];
  const int* neg_link_dst = (const int*)d_in[9];
  const float* lam = (const float*)d_in[10];
  const float* gat_Wsrc = (const float*)d_in[11];
  const float* gat_bsrc = (const float*)d_in[12];
  const float* gat_Wdst = (const float*)d_in[13];
  const float* gat_bdst = (const float*)d_in[14];
  const float* gat_attn = (const float*)d_in[15];
  const float* W_out = (const float*)d_in[16];
  const float* b_out = (const float*)d_in[17];
  const float* cheb_W = (const float*)d_in[18];
  const float* cheb_b = (const float*)d_in[19];
  const float* Wc = (const float*)d_in[20];
  const float* bc = (const float*)d_in[21];
  const float* Wsm = (const float*)d_in[22];
  const float* bs = (const float*)d_in[23];
  const float* WpP = (const float*)d_in[24];
  const float* bpP = (const float*)d_in[25];
  const float* WpS = (const float*)d_in[26];
  const float* bpS = (const float*)d_in[27];

  const int NU = in_sizes[0] / 64;
  const int NI = in_sizes[1] / 64;
  const int NR = in_sizes[2];
  const int NL = in_sizes[4];
  const int NMAX = NU > NI ? NU : NI;
  const size_t MAT = (size_t)NMAX * 64;

  float* ws = (float*)d_ws;
  float* B0 = ws + 0 * MAT;  // fs scratch / cheb h
  float* B1 = ws + 1 * MAT;  // fd scratch
  float* B2 = ws + 2 * MAT;  // h1_item (raw) -> T1 -> h_mP
  float* B3 = ws + 3 * MAT;  // h2_user (raw) -> T2 -> h_mS
  float* B4 = ws + 4 * MAT;  // item_infl (raw) -> h_uP
  float* B5 = ws + 5 * MAT;  // social_item (raw) -> h_uS
  float* B6 = ws + 6 * MAT;  // user_pref -> h_new_P
  float* B7 = ws + 7 * MAT;  // rst -> h_new_S
  float* B8 = ws + 8 * MAT;  // user_social (raw)
  float* den0 = ws + 9 * MAT;          // NI (gat0: per-item)
  float* den1 = den0 + NMAX;           // NU (gat1)
  float* den2 = den1 + NMAX;           // NU (gat2)
  float* den3 = den2 + NMAX;           // NU (gat3)
  float* den4 = den3 + NMAX;           // NU (gat4)
  float* dinv = den4 + NMAX;           // NU

  const int W64 = 64 * 64, B64 = 64;

  // ---- gat0: user -> item over rate edges (raw out B2, den0) ----
  run_gat(user_emb, NU, nullptr, item_emb, NI, nullptr,
          gat_Wsrc + 0 * W64, gat_bsrc + 0 * B64, gat_Wdst + 0 * W64,
          gat_bdst + 0 * B64, gat_attn + 0 * B64,
          rate_src, rate_dst, NR, B0, B1, B2, den0, stream);
  // ---- gat1: item -> user (reverse rate) (raw out B3, den1) ----
  run_gat(item_emb, NI, nullptr, user_emb, NU, nullptr,
          gat_Wsrc + 1 * W64, gat_bsrc + 1 * B64, gat_Wdst + 1 * W64,
          gat_bdst + 1 * B64, gat_attn + 1 * B64,
          rate_dst, rate_src, NR, B0, B1, B3, den1, stream);
  // ---- gat2: h1_item(/den0) -> user (raw out B4, den2) ----
  run_gat(B2, NI, den0, user_emb, NU, nullptr,
          gat_Wsrc + 2 * W64, gat_bsrc + 2 * B64, gat_Wdst + 2 * W64,
          gat_bdst + 2 * B64, gat_attn + 2 * B64,
          rate_dst, rate_src, NR, B0, B1, B4, den2, stream);
  // ---- gat3: h2_user(/den1) -> user over link edges (raw out B5, den3) ----
  run_gat(B3, NU, den1, user_emb, NU, nullptr,
          gat_Wsrc + 3 * W64, gat_bsrc + 3 * B64, gat_Wdst + 3 * W64,
          gat_bdst + 3 * B64, gat_attn + 3 * B64,
          link_src, link_dst, NL, B0, B1, B5, den3, stream);
  // ---- user_pref = [item_infl/den2, social_item/den3] @ W_out + b_out -> B6 ----
  gemm128_k<<<GEMM_BLOCKS, 256, 0, stream>>>(B4, B5, W_out, b_out, den2, den3, B6, NU);

  // ---- ChebConv(k=3) on link graph ----
  hipMemsetAsync(dinv, 0, (size_t)NU * 4, stream);
  indeg_k<<<(NL + 255) / 256, 256, 0, stream>>>(link_dst, dinv, NL);
  dinv_k<<<(NU + 255) / 256, 256, 0, stream>>>(dinv, NU);
  const int TOT = NU * 64;
  hipMemsetAsync(B0, 0, (size_t)TOT * 4, stream);
  ahat_k<<<EDGE_BLOCKS, 256, 0, stream>>>(user_emb, dinv, link_src, link_dst, B0, NL);
  t1_k<<<EDGE_BLOCKS, 256, 0, stream>>>((const float4*)B0, (const float4*)user_emb,
                                        dinv, lam, (float4*)B2, TOT / 4);
  hipMemsetAsync(B0, 0, (size_t)TOT * 4, stream);
  ahat_k<<<EDGE_BLOCKS, 256, 0, stream>>>(B2, dinv, link_src, link_dst, B0, NL);
  t2_k<<<EDGE_BLOCKS, 256, 0, stream>>>((const float4*)B0, (const float4*)B2,
                                        (const float4*)user_emb, dinv, lam,
                                        (float4*)B3, TOT / 4);
  cheb3_k<<<GEMM_BLOCKS, 256, 0, stream>>>(user_emb, B2, B3, cheb_W, cheb_b, B7, NU);

  // ---- gat4: rst -> rst over link edges (raw out B8, den4) ----
  run_gat(B7, NU, nullptr, B7, NU, nullptr,
          gat_Wsrc + 4 * W64, gat_bsrc + 4 * B64, gat_Wdst + 4 * W64,
          gat_bdst + 4 * B64, gat_attn + 4 * B64,
          link_src, link_dst, NL, B0, B1, B8, den4, stream);

  // ---- mutualistic ----
  gemm128_k<<<GEMM_BLOCKS, 256, 0, stream>>>(B6, user_emb, Wc, bc, nullptr, nullptr, B4, NU);   // h_uP
  gemm128_k<<<GEMM_BLOCKS, 256, 0, stream>>>(B8, user_emb, Wsm, bs, den4, nullptr, B5, NU);     // h_uS
  mut_k<<<(NU + 3) / 4, 256, 0, stream>>>(B4, B5, B2, B3, NU);                                  // h_mP, h_mS
  gemm128_k<<<GEMM_BLOCKS, 256, 0, stream>>>(B2, B4, WpP, bpP, nullptr, nullptr, B6, NU);       // h_new_P
  gemm128_k<<<GEMM_BLOCKS, 256, 0, stream>>>(B3, B5, WpS, bpS, nullptr, nullptr, B7, NU);       // h_new_S

  // ---- predictors ----
  float* out = (float*)d_out;
  dot_k<<<EDGE_BLOCKS, 256, 0, stream>>>(B6, item_emb, rate_src, rate_dst, out, NR);
  dot_k<<<EDGE_BLOCKS, 256, 0, stream>>>(B6, item_emb, neg_rate_src, neg_rate_dst, out + NR, NR);
  dot_k<<<EDGE_BLOCKS, 256, 0, stream>>>(B7, user_emb, link_src, link_dst, out + 2 * (size_t)NR, NL);
  dot_k<<<EDGE_BLOCKS, 256, 0, stream>>>(B7, user_emb, neg_link_src, neg_link_dst, out + 2 * (size_t)NR + NL, NL);
}

// Round 4
// 2398.706 us; speedup vs baseline: 8.1443x; 8.1443x over previous
//
#include <hip/hip_runtime.h>

// ---------------------------------------------------------------------------
// MutualRec forward: 5x GATv2 + ChebConv(k=3) + mutualistic MLP + edge dots
// R3: scalar-broadcast GEMM (row index -> readfirstlane -> s_load X; W in LDS;
//     4 rows share each ds_read). No shfl in GEMMs. Unified gemm_multi<NMAT>
//     covers gemm64 / gemm128 / cheb-combine with den-folding at combine.
// Edge kernels: single-pass GAT (exp without max-sub; normalization folded
//     into consuming GEMM), validated in R2/R3 runs.
// ---------------------------------------------------------------------------

#define LRELU_SLOPE 0.2f
#define GEMM_BLOCKS 1024
#define EDGE_BLOCKS 2048

// ---- Y[N,64] = sum_m norm_m(X_m) @ W[m] + b ----
// W is [NMAT*64, 64] row-major (stacked 64x64 blocks).
// den0/den1 (optional) normalize X0/X1 rows: row /= den[row] (0 if den==0).
template <int NMAT>
__global__ void gemm_multi_k(const float* __restrict__ X0,
                             const float* __restrict__ X1,
                             const float* __restrict__ X2,
                             const float* __restrict__ W,
                             const float* __restrict__ b,
                             const float* __restrict__ den0,
                             const float* __restrict__ den1,
                             float* __restrict__ Y, int N) {
  __shared__ float Ws[NMAT * 4096];
  for (int i = threadIdx.x; i < NMAT * 4096; i += 256) Ws[i] = W[i];
  __syncthreads();
  const int lane = threadIdx.x & 63;
  const int gw = (blockIdx.x * 256 + threadIdx.x) >> 6;
  const int nw = (gridDim.x * 256) >> 6;
  const float bj = b[lane];
  for (int r0 = gw * 4; r0 < N; r0 += nw * 4) {
    // wave-uniform row bases -> scalar loads for X
    const int ru = __builtin_amdgcn_readfirstlane(r0);
    const int r1 = (ru + 1 < N) ? ru + 1 : ru;
    const int r2 = (ru + 2 < N) ? ru + 2 : ru;
    const int r3 = (ru + 3 < N) ? ru + 3 : ru;
    float acc[NMAT][4];
#pragma unroll
    for (int m = 0; m < NMAT; ++m) {
      acc[m][0] = 0.0f; acc[m][1] = 0.0f; acc[m][2] = 0.0f; acc[m][3] = 0.0f;
    }
#pragma unroll
    for (int m = 0; m < NMAT; ++m) {
      const float* Xm = (m == 0) ? X0 : ((m == 1) ? X1 : X2);
      const float* xr0 = Xm + (size_t)ru * 64;
      const float* xr1 = Xm + (size_t)r1 * 64;
      const float* xr2 = Xm + (size_t)r2 * 64;
      const float* xr3 = Xm + (size_t)r3 * 64;
      const float* wm = Ws + m * 4096;
#pragma unroll 1
      for (int kc = 0; kc < 64; kc += 16) {
#pragma unroll
        for (int kk = 0; kk < 16; ++kk) {
          const int k = kc + kk;
          const float w = wm[k * 64 + lane];   // ds_read, shared by 4 rows
          acc[m][0] = fmaf(xr0[k], w, acc[m][0]);  // s_load operands
          acc[m][1] = fmaf(xr1[k], w, acc[m][1]);
          acc[m][2] = fmaf(xr2[k], w, acc[m][2]);
          acc[m][3] = fmaf(xr3[k], w, acc[m][3]);
        }
      }
    }
    float y0 = bj, y1 = bj, y2 = bj, y3 = bj;
#pragma unroll
    for (int m = 0; m < NMAT; ++m) {
      const float* dn = (m == 0) ? den0 : ((m == 1) ? den1 : nullptr);
      float i0 = 1.0f, i1 = 1.0f, i2 = 1.0f, i3 = 1.0f;
      if (dn) {
        const float d0 = dn[ru], d1 = dn[r1], d2 = dn[r2], d3 = dn[r3];
        i0 = d0 > 0.0f ? 1.0f / d0 : 0.0f;
        i1 = d1 > 0.0f ? 1.0f / d1 : 0.0f;
        i2 = d2 > 0.0f ? 1.0f / d2 : 0.0f;
        i3 = d3 > 0.0f ? 1.0f / d3 : 0.0f;
      }
      y0 = fmaf(acc[m][0], i0, y0);
      y1 = fmaf(acc[m][1], i1, y1);
      y2 = fmaf(acc[m][2], i2, y2);
      y3 = fmaf(acc[m][3], i3, y3);
    }
    Y[(size_t)ru * 64 + lane] = y0;
    if (ru + 1 < N) Y[(size_t)(ru + 1) * 64 + lane] = y1;
    if (ru + 2 < N) Y[(size_t)(ru + 2) * 64 + lane] = y2;
    if (ru + 3 < N) Y[(size_t)(ru + 3) * 64 + lane] = y3;
  }
}

// ---- single-pass GATv2 edge kernel: score->exp->den/out atomics ----
// out[d] accumulates exp(s_e)*fs[src_e]; den[d] accumulates exp(s_e).
// Normalization happens in the consuming GEMM (division by den).
__global__ void gat_edge_k(const float* __restrict__ fs, const float* __restrict__ fd,
                           const float* __restrict__ attn, const int* __restrict__ src,
                           const int* __restrict__ dst, float* __restrict__ den,
                           float* __restrict__ out, int E) {
  const int lane = threadIdx.x & 63;
  const int wid = (blockIdx.x * blockDim.x + threadIdx.x) >> 6;
  const int nw = (gridDim.x * blockDim.x) >> 6;
  const float aw = attn[lane];
  for (int e = wid; e < E; e += nw) {
    const int s = src[e], d = dst[e];
    const float fsv = fs[(size_t)s * 64 + lane];
    float v = fsv + fd[(size_t)d * 64 + lane];
    v = v > 0.0f ? v : LRELU_SLOPE * v;
    float p = v * aw;
#pragma unroll
    for (int o = 32; o; o >>= 1) p += __shfl_xor(p, o, 64);
    const float ex = __expf(p);
    if (lane == 0) atomicAdd(den + d, ex);
    atomicAdd(out + (size_t)d * 64 + lane, ex * fsv);
  }
}

// ---- Cheb: in-degree count ----
__global__ void indeg_k(const int* __restrict__ dst, float* __restrict__ deg, int E) {
  const int e = blockIdx.x * blockDim.x + threadIdx.x;
  if (e < E) atomicAdd(deg + dst[e], 1.0f);
}
__global__ void dinv_k(float* __restrict__ deg, int N) {
  const int i = blockIdx.x * blockDim.x + threadIdx.x;
  if (i < N) deg[i] = rsqrtf(fmaxf(deg[i], 1.0f));
}

// ---- Cheb: h[dst] += x[src]*dinv[src] (wave per edge, grid-stride) ----
__global__ void ahat_k(const float* __restrict__ x, const float* __restrict__ dinv,
                       const int* __restrict__ src, const int* __restrict__ dst,
                       float* __restrict__ h, int E) {
  const int lane = threadIdx.x & 63;
  const int wid = (blockIdx.x * blockDim.x + threadIdx.x) >> 6;
  const int nw = (gridDim.x * blockDim.x) >> 6;
  for (int e = wid; e < E; e += nw) {
    const int s = src[e], d = dst[e];
    atomicAdd(h + (size_t)d * 64 + lane, x[(size_t)s * 64 + lane] * dinv[s]);
  }
}

// ---- T1 = -re*(dinv*h) + (re-1)*T0  (float4) ----
__global__ void t1_k(const float4* __restrict__ h, const float4* __restrict__ T0,
                     const float* __restrict__ dinv, const float* __restrict__ lam,
                     float4* __restrict__ T1, int n4) {
  const float re = 2.0f / lam[0];
  const int stride = gridDim.x * blockDim.x;
  for (int i = blockIdx.x * blockDim.x + threadIdx.x; i < n4; i += stride) {
    const float sc = dinv[i >> 4];
    const float4 hv = h[i], t0 = T0[i];
    float4 r;
    r.x = -re * (sc * hv.x) + (re - 1.0f) * t0.x;
    r.y = -re * (sc * hv.y) + (re - 1.0f) * t0.y;
    r.z = -re * (sc * hv.z) + (re - 1.0f) * t0.z;
    r.w = -re * (sc * hv.w) + (re - 1.0f) * t0.w;
    T1[i] = r;
  }
}

// ---- T2 = -2re*(dinv*h2) + 2(re-1)*T1 - T0  (float4) ----
__global__ void t2_k(const float4* __restrict__ h2, const float4* __restrict__ T1,
                     const float4* __restrict__ T0, const float* __restrict__ dinv,
                     const float* __restrict__ lam, float4* __restrict__ T2, int n4) {
  const float re = 2.0f / lam[0];
  const int stride = gridDim.x * blockDim.x;
  for (int i = blockIdx.x * blockDim.x + threadIdx.x; i < n4; i += stride) {
    const float sc = dinv[i >> 4];
    const float4 hv = h2[i], t1 = T1[i], t0 = T0[i];
    float4 r;
    r.x = -2.0f * re * (sc * hv.x) + 2.0f * (re - 1.0f) * t1.x - t0.x;
    r.y = -2.0f * re * (sc * hv.y) + 2.0f * (re - 1.0f) * t1.y - t0.y;
    r.z = -2.0f * re * (sc * hv.z) + 2.0f * (re - 1.0f) * t1.z - t0.z;
    r.w = -2.0f * re * (sc * hv.w) + 2.0f * (re - 1.0f) * t1.w - t0.w;
    T2[i] = r;
  }
}

// ---- mutualistic: mP = (p*s)*softmax(p), mS = (p*s)*softmax(s) (wave/row) ----
__global__ void mut_k(const float* __restrict__ hP, const float* __restrict__ hS,
                      float* __restrict__ mP, float* __restrict__ mS, int N) {
  const int lane = threadIdx.x & 63;
  const int u = (blockIdx.x * blockDim.x + threadIdx.x) >> 6;
  if (u >= N) return;
  const float p = hP[(size_t)u * 64 + lane];
  const float s = hS[(size_t)u * 64 + lane];
  const float m = p * s;
  float mxp = p, mxs = s;
#pragma unroll
  for (int o = 32; o; o >>= 1) {
    mxp = fmaxf(mxp, __shfl_xor(mxp, o, 64));
    mxs = fmaxf(mxs, __shfl_xor(mxs, o, 64));
  }
  float ep = __expf(p - mxp);
  float es = __expf(s - mxs);
  float sp = ep, ss = es;
#pragma unroll
  for (int o = 32; o; o >>= 1) {
    sp += __shfl_xor(sp, o, 64);
    ss += __shfl_xor(ss, o, 64);
  }
  mP[(size_t)u * 64 + lane] = m * (ep / sp);
  mS[(size_t)u * 64 + lane] = m * (es / ss);
}

// ---- edge dot: out[e] = <A[src[e]], B[dst[e]]> (wave per edge, ILP-2) ----
__global__ void dot_k(const float* __restrict__ A, const float* __restrict__ Bm,
                      const int* __restrict__ src, const int* __restrict__ dst,
                      float* __restrict__ out, int E) {
  const int lane = threadIdx.x & 63;
  const int wid = (blockIdx.x * blockDim.x + threadIdx.x) >> 6;
  const int nw = (gridDim.x * blockDim.x) >> 6;
  for (int e0 = wid * 2; e0 < E; e0 += nw * 2) {
    const bool has1 = (e0 + 1 < E);
    const int s0 = src[e0], d0 = dst[e0];
    const int s1 = has1 ? src[e0 + 1] : s0;
    const int d1 = has1 ? dst[e0 + 1] : d0;
    float p0 = A[(size_t)s0 * 64 + lane] * Bm[(size_t)d0 * 64 + lane];
    float p1 = A[(size_t)s1 * 64 + lane] * Bm[(size_t)d1 * 64 + lane];
#pragma unroll
    for (int o = 32; o; o >>= 1) {
      p0 += __shfl_xor(p0, o, 64);
      p1 += __shfl_xor(p1, o, 64);
    }
    if (lane == 0) {
      out[e0] = p0;
      if (has1) out[e0 + 1] = p1;
    }
  }
}

// ---------------------------------------------------------------------------

static void run_gat(const float* hsrc, int Ns, const float* dsrc_den,
                    const float* hdst, int Nd, const float* ddst_den,
                    const float* Wsrc, const float* bsrc,
                    const float* Wdst, const float* bdst, const float* attn,
                    const int* src, const int* dst, int E,
                    float* fs, float* fd, float* out, float* den,
                    hipStream_t stream) {
  gemm_multi_k<1><<<GEMM_BLOCKS, 256, 0, stream>>>(
      hsrc, nullptr, nullptr, Wsrc, bsrc, dsrc_den, nullptr, fs, Ns);
  gemm_multi_k<1><<<GEMM_BLOCKS, 256, 0, stream>>>(
      hdst, nullptr, nullptr, Wdst, bdst, ddst_den, nullptr, fd, Nd);
  hipMemsetAsync(den, 0, (size_t)Nd * 4, stream);
  hipMemsetAsync(out, 0, (size_t)Nd * 64 * 4, stream);
  gat_edge_k<<<EDGE_BLOCKS, 256, 0, stream>>>(fs, fd, attn, src, dst, den, out, E);
}

extern "C" void kernel_launch(void* const* d_in, const int* in_sizes, int n_in,
                              void* d_out, int out_size, void* d_ws, size_t ws_size,
                              hipStream_t stream) {
  const float* user_emb = (const float*)d_in[0];
  const float* item_emb = (const float*)d_in[1];
  const int* rate_src = (const int*)d_in[2];
  const int* rate_dst = (const int*)d_in[3];
  const int* link_src = (const int*)d_in[4];
  const int* link_dst = (const int*)d_in[5];
  const int* neg_rate_src = (const int*)d_in[6];
  const int* neg_rate_dst = (const int*)d_in[7];
  const int* neg_link_src = (const int*)d_in[8];
  const int* neg_link_dst = (const int*)d_in[9];
  const float* lam = (const float*)d_in[10];
  const float* gat_Wsrc = (const float*)d_in[11];
  const float* gat_bsrc = (const float*)d_in[12];
  const float* gat_Wdst = (const float*)d_in[13];
  const float* gat_bdst = (const float*)d_in[14];
  const float* gat_attn = (const float*)d_in[15];
  const float* W_out = (const float*)d_in[16];
  const float* b_out = (const float*)d_in[17];
  const float* cheb_W = (const float*)d_in[18];
  const float* cheb_b = (const float*)d_in[19];
  const float* Wc = (const float*)d_in[20];
  const float* bc = (const float*)d_in[21];
  const float* Wsm = (const float*)d_in[22];
  const float* bs = (const float*)d_in[23];
  const float* WpP = (const float*)d_in[24];
  const float* bpP = (const float*)d_in[25];
  const float* WpS = (const float*)d_in[26];
  const float* bpS = (const float*)d_in[27];

  const int NU = in_sizes[0] / 64;
  const int NI = in_sizes[1] / 64;
  const int NR = in_sizes[2];
  const int NL = in_sizes[4];
  const int NMAX = NU > NI ? NU : NI;
  const size_t MAT = (size_t)NMAX * 64;

  float* ws = (float*)d_ws;
  float* B0 = ws + 0 * MAT;  // fs scratch / cheb h
  float* B1 = ws + 1 * MAT;  // fd scratch
  float* B2 = ws + 2 * MAT;  // h1_item (raw) -> T1 -> h_mP
  float* B3 = ws + 3 * MAT;  // h2_user (raw) -> T2 -> h_mS
  float* B4 = ws + 4 * MAT;  // item_infl (raw) -> h_uP
  float* B5 = ws + 5 * MAT;  // social_item (raw) -> h_uS
  float* B6 = ws + 6 * MAT;  // user_pref -> h_new_P
  float* B7 = ws + 7 * MAT;  // rst -> h_new_S
  float* B8 = ws + 8 * MAT;  // user_social (raw)
  float* den0 = ws + 9 * MAT;          // NI (gat0: per-item)
  float* den1 = den0 + NMAX;           // NU (gat1)
  float* den2 = den1 + NMAX;           // NU (gat2)
  float* den3 = den2 + NMAX;           // NU (gat3)
  float* den4 = den3 + NMAX;           // NU (gat4)
  float* dinv = den4 + NMAX;           // NU

  const int W64 = 64 * 64, B64 = 64;

  // ---- gat0: user -> item over rate edges (raw out B2, den0) ----
  run_gat(user_emb, NU, nullptr, item_emb, NI, nullptr,
          gat_Wsrc + 0 * W64, gat_bsrc + 0 * B64, gat_Wdst + 0 * W64,
          gat_bdst + 0 * B64, gat_attn + 0 * B64,
          rate_src, rate_dst, NR, B0, B1, B2, den0, stream);
  // ---- gat1: item -> user (reverse rate) (raw out B3, den1) ----
  run_gat(item_emb, NI, nullptr, user_emb, NU, nullptr,
          gat_Wsrc + 1 * W64, gat_bsrc + 1 * B64, gat_Wdst + 1 * W64,
          gat_bdst + 1 * B64, gat_attn + 1 * B64,
          rate_dst, rate_src, NR, B0, B1, B3, den1, stream);
  // ---- gat2: h1_item(/den0) -> user (raw out B4, den2) ----
  run_gat(B2, NI, den0, user_emb, NU, nullptr,
          gat_Wsrc + 2 * W64, gat_bsrc + 2 * B64, gat_Wdst + 2 * W64,
          gat_bdst + 2 * B64, gat_attn + 2 * B64,
          rate_dst, rate_src, NR, B0, B1, B4, den2, stream);
  // ---- gat3: h2_user(/den1) -> user over link edges (raw out B5, den3) ----
  run_gat(B3, NU, den1, user_emb, NU, nullptr,
          gat_Wsrc + 3 * W64, gat_bsrc + 3 * B64, gat_Wdst + 3 * W64,
          gat_bdst + 3 * B64, gat_attn + 3 * B64,
          link_src, link_dst, NL, B0, B1, B5, den3, stream);
  // ---- user_pref = [item_infl/den2, social_item/den3] @ W_out + b_out -> B6 ----
  gemm_multi_k<2><<<GEMM_BLOCKS, 256, 0, stream>>>(
      B4, B5, nullptr, W_out, b_out, den2, den3, B6, NU);

  // ---- ChebConv(k=3) on link graph ----
  hipMemsetAsync(dinv, 0, (size_t)NU * 4, stream);
  indeg_k<<<(NL + 255) / 256, 256, 0, stream>>>(link_dst, dinv, NL);
  dinv_k<<<(NU + 255) / 256, 256, 0, stream>>>(dinv, NU);
  const int TOT = NU * 64;
  hipMemsetAsync(B0, 0, (size_t)TOT * 4, stream);
  ahat_k<<<EDGE_BLOCKS, 256, 0, stream>>>(user_emb, dinv, link_src, link_dst, B0, NL);
  t1_k<<<EDGE_BLOCKS, 256, 0, stream>>>((const float4*)B0, (const float4*)user_emb,
                                        dinv, lam, (float4*)B2, TOT / 4);
  hipMemsetAsync(B0, 0, (size_t)TOT * 4, stream);
  ahat_k<<<EDGE_BLOCKS, 256, 0, stream>>>(B2, dinv, link_src, link_dst, B0, NL);
  t2_k<<<EDGE_BLOCKS, 256, 0, stream>>>((const float4*)B0, (const float4*)B2,
                                        (const float4*)user_emb, dinv, lam,
                                        (float4*)B3, TOT / 4);
  // rst = T0@W0 + T1@W1 + T2@W2 + b -> B7
  gemm_multi_k<3><<<GEMM_BLOCKS, 256, 0, stream>>>(
      user_emb, B2, B3, cheb_W, cheb_b, nullptr, nullptr, B7, NU);

  // ---- gat4: rst -> rst over link edges (raw out B8, den4) ----
  run_gat(B7, NU, nullptr, B7, NU, nullptr,
          gat_Wsrc + 4 * W64, gat_bsrc + 4 * B64, gat_Wdst + 4 * W64,
          gat_bdst + 4 * B64, gat_attn + 4 * B64,
          link_src, link_dst, NL, B0, B1, B8, den4, stream);

  // ---- mutualistic ----
  gemm_multi_k<2><<<GEMM_BLOCKS, 256, 0, stream>>>(
      B6, user_emb, nullptr, Wc, bc, nullptr, nullptr, B4, NU);   // h_uP
  gemm_multi_k<2><<<GEMM_BLOCKS, 256, 0, stream>>>(
      B8, user_emb, nullptr, Wsm, bs, den4, nullptr, B5, NU);     // h_uS
  mut_k<<<(NU + 3) / 4, 256, 0, stream>>>(B4, B5, B2, B3, NU);    // h_mP, h_mS
  gemm_multi_k<2><<<GEMM_BLOCKS, 256, 0, stream>>>(
      B2, B4, nullptr, WpP, bpP, nullptr, nullptr, B6, NU);       // h_new_P
  gemm_multi_k<2><<<GEMM_BLOCKS, 256, 0, stream>>>(
      B3, B5, nullptr, WpS, bpS, nullptr, nullptr, B7, NU);       // h_new_S

  // ---- predictors ----
  float* out = (float*)d_out;
  dot_k<<<EDGE_BLOCKS, 256, 0, stream>>>(B6, item_emb, rate_src, rate_dst, out, NR);
  dot_k<<<EDGE_BLOCKS, 256, 0, stream>>>(B6, item_emb, neg_rate_src, neg_rate_dst, out + NR, NR);
  dot_k<<<EDGE_BLOCKS, 256, 0, stream>>>(B7, user_emb, link_src, link_dst, out + 2 * (size_t)NR, NL);
  dot_k<<<EDGE_BLOCKS, 256, 0, stream>>>(B7, user_emb, neg_link_src, neg_link_dst, out + 2 * (size_t)NR + NL, NL);
}

// Round 5
// 1785.413 us; speedup vs baseline: 10.9419x; 1.3435x over previous
//
#include <hip/hip_runtime.h>

// ---------------------------------------------------------------------------
// MutualRec forward: 5x GATv2 + ChebConv(k=3) + mutualistic MLP + edge dots
// R4->R5: on-device CSR build (counting sort by dst) for 3 edge groupings;
//   GAT aggregation + Cheb ahat become atomic-free wave-per-node kernels
//   (register accumulate, one streaming store per row). Normalization done
//   in-register; den plumbing removed from GEMMs. indeg from rowptr.
// GEMMs: scalar-broadcast (s_load X rows, W in LDS), unchanged from R4.
// ---------------------------------------------------------------------------

#define LRELU_SLOPE 0.2f
#define GEMM_BLOCKS 1024
#define EDGE_BLOCKS 2048

// ============================ GEMM family ==================================
// Y[N,64] = sum_m X_m[N,64] @ W[m] + b ; W is [NMAT*64,64] row-major stacked.
template <int NMAT>
__global__ void gemm_multi_k(const float* __restrict__ X0,
                             const float* __restrict__ X1,
                             const float* __restrict__ X2,
                             const float* __restrict__ W,
                             const float* __restrict__ b,
                             float* __restrict__ Y, int N) {
  __shared__ float Ws[NMAT * 4096];
  for (int i = threadIdx.x; i < NMAT * 4096; i += 256) Ws[i] = W[i];
  __syncthreads();
  const int lane = threadIdx.x & 63;
  const int gw = (blockIdx.x * 256 + threadIdx.x) >> 6;
  const int nw = (gridDim.x * 256) >> 6;
  const float bj = b[lane];
  for (int r0 = gw * 4; r0 < N; r0 += nw * 4) {
    const int ru = __builtin_amdgcn_readfirstlane(r0);
    const int r1 = (ru + 1 < N) ? ru + 1 : ru;
    const int r2 = (ru + 2 < N) ? ru + 2 : ru;
    const int r3 = (ru + 3 < N) ? ru + 3 : ru;
    float y0 = bj, y1 = bj, y2 = bj, y3 = bj;
#pragma unroll
    for (int m = 0; m < NMAT; ++m) {
      const float* Xm = (m == 0) ? X0 : ((m == 1) ? X1 : X2);
      const float* xr0 = Xm + (size_t)ru * 64;
      const float* xr1 = Xm + (size_t)r1 * 64;
      const float* xr2 = Xm + (size_t)r2 * 64;
      const float* xr3 = Xm + (size_t)r3 * 64;
      const float* wm = Ws + m * 4096;
#pragma unroll 1
      for (int kc = 0; kc < 64; kc += 16) {
#pragma unroll
        for (int kk = 0; kk < 16; ++kk) {
          const int k = kc + kk;
          const float w = wm[k * 64 + lane];   // ds_read shared by 4 rows
          y0 = fmaf(xr0[k], w, y0);            // s_load operands
          y1 = fmaf(xr1[k], w, y1);
          y2 = fmaf(xr2[k], w, y2);
          y3 = fmaf(xr3[k], w, y3);
        }
      }
    }
    Y[(size_t)ru * 64 + lane] = y0;
    if (ru + 1 < N) Y[(size_t)(ru + 1) * 64 + lane] = y1;
    if (ru + 2 < N) Y[(size_t)(ru + 2) * 64 + lane] = y2;
    if (ru + 3 < N) Y[(size_t)(ru + 3) * 64 + lane] = y3;
  }
}

// ========================= CSR build (counting sort) =======================
__global__ void hist_k(const int* __restrict__ key, int* __restrict__ cnt, int E) {
  const int e = blockIdx.x * blockDim.x + threadIdx.x;
  if (e < E) atomicAdd(cnt + key[e], 1);
}

// exclusive scan, 1024 elements per block (256 thr x 4)
__global__ void scan1_k(const int* __restrict__ in, int* __restrict__ out,
                        int* __restrict__ bsum, int n) {
  __shared__ int tmp[256];
  const int t = threadIdx.x;
  const int base = blockIdx.x * 1024 + t * 4;
  int v0 = (base + 0 < n) ? in[base + 0] : 0;
  int v1 = (base + 1 < n) ? in[base + 1] : 0;
  int v2 = (base + 2 < n) ? in[base + 2] : 0;
  int v3 = (base + 3 < n) ? in[base + 3] : 0;
  const int s = v0 + v1 + v2 + v3;
  tmp[t] = s;
  __syncthreads();
  for (int off = 1; off < 256; off <<= 1) {
    const int x = (t >= off) ? tmp[t - off] : 0;
    __syncthreads();
    tmp[t] += x;
    __syncthreads();
  }
  const int excl = tmp[t] - s;
  if (t == 255) bsum[blockIdx.x] = tmp[255];
  if (base + 0 < n) out[base + 0] = excl;
  if (base + 1 < n) out[base + 1] = excl + v0;
  if (base + 2 < n) out[base + 2] = excl + v0 + v1;
  if (base + 3 < n) out[base + 3] = excl + v0 + v1 + v2;
}
__global__ void scan2_k(int* __restrict__ bsum, int nb) {
  if (threadIdx.x == 0) {
    int acc = 0;
    for (int i = 0; i < nb; ++i) { const int v = bsum[i]; bsum[i] = acc; acc += v; }
  }
}
__global__ void scan3_k(int* __restrict__ out, const int* __restrict__ bsum, int n) {
  const int i = blockIdx.x * blockDim.x + threadIdx.x;
  if (i < n) out[i] += bsum[i >> 10];
}

__global__ void scatter_k(const int* __restrict__ key, const int* __restrict__ other,
                          int* __restrict__ cursor, int* __restrict__ srt, int E) {
  const int e = blockIdx.x * blockDim.x + threadIdx.x;
  if (e < E) {
    const int p = atomicAdd(cursor + key[e], 1);
    srt[p] = other[e];
  }
}

// ======================= CSR-based graph kernels ===========================
// GATv2 aggregate+normalize, wave per dst node:
// out[n] = ( sum_e exp(attn . lrelu(fs[nbr_e]+fd[n])) * fs[nbr_e] ) / sum_e exp(.)
__global__ void gat_csr_k(const float* __restrict__ fs, const float* __restrict__ fd,
                          const float* __restrict__ attn,
                          const int* __restrict__ rowptr, const int* __restrict__ nbr,
                          float* __restrict__ out, int N) {
  const int lane = threadIdx.x & 63;
  const int wid = (blockIdx.x * blockDim.x + threadIdx.x) >> 6;
  const int nw = (gridDim.x * blockDim.x) >> 6;
  const float aw = attn[lane];
  for (int n = wid; n < N; n += nw) {
    const int beg = rowptr[n], end = rowptr[n + 1];
    const float fdv = fd[(size_t)n * 64 + lane];
    float acc = 0.0f, den = 0.0f;
    int e = beg;
    for (; e + 1 < end; e += 2) {
      const int s0 = nbr[e], s1 = nbr[e + 1];
      const float f0 = fs[(size_t)s0 * 64 + lane];
      const float f1 = fs[(size_t)s1 * 64 + lane];
      float v0 = f0 + fdv; v0 = v0 > 0.0f ? v0 : LRELU_SLOPE * v0;
      float v1 = f1 + fdv; v1 = v1 > 0.0f ? v1 : LRELU_SLOPE * v1;
      float p0 = v0 * aw, p1 = v1 * aw;
#pragma unroll
      for (int o = 32; o; o >>= 1) {
        p0 += __shfl_xor(p0, o, 64);
        p1 += __shfl_xor(p1, o, 64);
      }
      const float e0 = __expf(p0), e1 = __expf(p1);
      den += e0 + e1;
      acc = fmaf(e0, f0, acc);
      acc = fmaf(e1, f1, acc);
    }
    if (e < end) {
      const int s0 = nbr[e];
      const float f0 = fs[(size_t)s0 * 64 + lane];
      float v0 = f0 + fdv; v0 = v0 > 0.0f ? v0 : LRELU_SLOPE * v0;
      float p0 = v0 * aw;
#pragma unroll
      for (int o = 32; o; o >>= 1) p0 += __shfl_xor(p0, o, 64);
      const float e0 = __expf(p0);
      den += e0;
      acc = fmaf(e0, f0, acc);
    }
    const float inv = den > 0.0f ? 1.0f / den : 0.0f;
    out[(size_t)n * 64 + lane] = acc * inv;
  }
}

// h[n] = dinv[n] * sum_e x[nbr_e]*dinv[nbr_e]   (full ahat, wave per node)
__global__ void ahat_csr_k(const float* __restrict__ x, const float* __restrict__ dinv,
                           const int* __restrict__ rowptr, const int* __restrict__ nbr,
                           float* __restrict__ h, int N) {
  const int lane = threadIdx.x & 63;
  const int wid = (blockIdx.x * blockDim.x + threadIdx.x) >> 6;
  const int nw = (gridDim.x * blockDim.x) >> 6;
  for (int n = wid; n < N; n += nw) {
    const int beg = rowptr[n], end = rowptr[n + 1];
    float acc = 0.0f;
    int e = beg;
    for (; e + 1 < end; e += 2) {
      const int s0 = nbr[e], s1 = nbr[e + 1];
      acc = fmaf(x[(size_t)s0 * 64 + lane], dinv[s0], acc);
      acc = fmaf(x[(size_t)s1 * 64 + lane], dinv[s1], acc);
    }
    if (e < end) {
      const int s0 = nbr[e];
      acc = fmaf(x[(size_t)s0 * 64 + lane], dinv[s0], acc);
    }
    h[(size_t)n * 64 + lane] = acc * dinv[n];
  }
}

// dinv[i] = rsqrt(max(deg,1)) from rowptr diff
__global__ void dinv_k(const int* __restrict__ rowptr, float* __restrict__ dinv, int N) {
  const int i = blockIdx.x * blockDim.x + threadIdx.x;
  if (i < N) {
    const float deg = (float)(rowptr[i + 1] - rowptr[i]);
    dinv[i] = rsqrtf(fmaxf(deg, 1.0f));
  }
}

// ---- T1 = -re*h + (re-1)*T0  (h pre-scaled; float4) ----
__global__ void t1_k(const float4* __restrict__ h, const float4* __restrict__ T0,
                     const float* __restrict__ lam, float4* __restrict__ T1, int n4) {
  const float re = 2.0f / lam[0];
  const int stride = gridDim.x * blockDim.x;
  for (int i = blockIdx.x * blockDim.x + threadIdx.x; i < n4; i += stride) {
    const float4 hv = h[i], t0 = T0[i];
    float4 r;
    r.x = -re * hv.x + (re - 1.0f) * t0.x;
    r.y = -re * hv.y + (re - 1.0f) * t0.y;
    r.z = -re * hv.z + (re - 1.0f) * t0.z;
    r.w = -re * hv.w + (re - 1.0f) * t0.w;
    T1[i] = r;
  }
}

// ---- T2 = -2re*h2 + 2(re-1)*T1 - T0  (float4) ----
__global__ void t2_k(const float4* __restrict__ h2, const float4* __restrict__ T1,
                     const float4* __restrict__ T0, const float* __restrict__ lam,
                     float4* __restrict__ T2, int n4) {
  const float re = 2.0f / lam[0];
  const int stride = gridDim.x * blockDim.x;
  for (int i = blockIdx.x * blockDim.x + threadIdx.x; i < n4; i += stride) {
    const float4 hv = h2[i], t1 = T1[i], t0 = T0[i];
    float4 r;
    r.x = -2.0f * re * hv.x + 2.0f * (re - 1.0f) * t1.x - t0.x;
    r.y = -2.0f * re * hv.y + 2.0f * (re - 1.0f) * t1.y - t0.y;
    r.z = -2.0f * re * hv.z + 2.0f * (re - 1.0f) * t1.z - t0.z;
    r.w = -2.0f * re * hv.w + 2.0f * (re - 1.0f) * t1.w - t0.w;
    T2[i] = r;
  }
}

// ---- mutualistic: mP = (p*s)*softmax(p), mS = (p*s)*softmax(s) (wave/row) ----
__global__ void mut_k(const float* __restrict__ hP, const float* __restrict__ hS,
                      float* __restrict__ mP, float* __restrict__ mS, int N) {
  const int lane = threadIdx.x & 63;
  const int u = (blockIdx.x * blockDim.x + threadIdx.x) >> 6;
  if (u >= N) return;
  const float p = hP[(size_t)u * 64 + lane];
  const float s = hS[(size_t)u * 64 + lane];
  const float m = p * s;
  float mxp = p, mxs = s;
#pragma unroll
  for (int o = 32; o; o >>= 1) {
    mxp = fmaxf(mxp, __shfl_xor(mxp, o, 64));
    mxs = fmaxf(mxs, __shfl_xor(mxs, o, 64));
  }
  const float ep = __expf(p - mxp);
  const float es = __expf(s - mxs);
  float sp = ep, ss = es;
#pragma unroll
  for (int o = 32; o; o >>= 1) {
    sp += __shfl_xor(sp, o, 64);
    ss += __shfl_xor(ss, o, 64);
  }
  mP[(size_t)u * 64 + lane] = m * (ep / sp);
  mS[(size_t)u * 64 + lane] = m * (es / ss);
}

// ---- edge dot: out[e] = <A[src[e]], B[dst[e]]> (wave per edge, ILP-2) ----
__global__ void dot_k(const float* __restrict__ A, const float* __restrict__ Bm,
                      const int* __restrict__ src, const int* __restrict__ dst,
                      float* __restrict__ out, int E) {
  const int lane = threadIdx.x & 63;
  const int wid = (blockIdx.x * blockDim.x + threadIdx.x) >> 6;
  const int nw = (gridDim.x * blockDim.x) >> 6;
  for (int e0 = wid * 2; e0 < E; e0 += nw * 2) {
    const bool has1 = (e0 + 1 < E);
    const int s0 = src[e0], d0 = dst[e0];
    const int s1 = has1 ? src[e0 + 1] : s0;
    const int d1 = has1 ? dst[e0 + 1] : d0;
    float p0 = A[(size_t)s0 * 64 + lane] * Bm[(size_t)d0 * 64 + lane];
    float p1 = A[(size_t)s1 * 64 + lane] * Bm[(size_t)d1 * 64 + lane];
#pragma unroll
    for (int o = 32; o; o >>= 1) {
      p0 += __shfl_xor(p0, o, 64);
      p1 += __shfl_xor(p1, o, 64);
    }
    if (lane == 0) {
      out[e0] = p0;
      if (has1) out[e0 + 1] = p1;
    }
  }
}

// ---------------------------------------------------------------------------

static void build_csr(const int* key, const int* other, int E, int N,
                      int* rowptr, int* srt, int* cnt, int* cursor, int* bsum,
                      hipStream_t stream) {
  const int n1 = N + 1;
  hipMemsetAsync(cnt, 0, (size_t)n1 * 4, stream);
  hist_k<<<(E + 255) / 256, 256, 0, stream>>>(key, cnt, E);
  const int nb = (n1 + 1023) / 1024;
  scan1_k<<<nb, 256, 0, stream>>>(cnt, rowptr, bsum, n1);
  scan2_k<<<1, 64, 0, stream>>>(bsum, nb);
  scan3_k<<<(n1 + 255) / 256, 256, 0, stream>>>(rowptr, bsum, n1);
  hipMemcpyAsync(cursor, rowptr, (size_t)N * 4, hipMemcpyDeviceToDevice, stream);
  scatter_k<<<(E + 255) / 256, 256, 0, stream>>>(key, other, cursor, srt, E);
}

static void run_gat(const float* hsrc, int Ns, const float* hdst, int Nd,
                    const float* Wsrc, const float* bsrc,
                    const float* Wdst, const float* bdst, const float* attn,
                    const int* rowptr, const int* nbr,
                    float* fs, float* fd, float* out, hipStream_t stream) {
  gemm_multi_k<1><<<GEMM_BLOCKS, 256, 0, stream>>>(hsrc, nullptr, nullptr, Wsrc, bsrc, fs, Ns);
  gemm_multi_k<1><<<GEMM_BLOCKS, 256, 0, stream>>>(hdst, nullptr, nullptr, Wdst, bdst, fd, Nd);
  gat_csr_k<<<EDGE_BLOCKS, 256, 0, stream>>>(fs, fd, attn, rowptr, nbr, out, Nd);
}

extern "C" void kernel_launch(void* const* d_in, const int* in_sizes, int n_in,
                              void* d_out, int out_size, void* d_ws, size_t ws_size,
                              hipStream_t stream) {
  const float* user_emb = (const float*)d_in[0];
  const float* item_emb = (const float*)d_in[1];
  const int* rate_src = (const int*)d_in[2];
  const int* rate_dst = (const int*)d_in[3];
  const int* link_src = (const int*)d_in[4];
  const int* link_dst = (const int*)d_in[5];
  const int* neg_rate_src = (const int*)d_in[6];
  const int* neg_rate_dst = (const int*)d_in[7];
  const int* neg_link_src = (const int*)d_in[8];
  const int* neg_link_dst = (const int*)d_in[9];
  const float* lam = (const float*)d_in[10];
  const float* gat_Wsrc = (const float*)d_in[11];
  const float* gat_bsrc = (const float*)d_in[12];
  const float* gat_Wdst = (const float*)d_in[13];
  const float* gat_bdst = (const float*)d_in[14];
  const float* gat_attn = (const float*)d_in[15];
  const float* W_out = (const float*)d_in[16];
  const float* b_out = (const float*)d_in[17];
  const float* cheb_W = (const float*)d_in[18];
  const float* cheb_b = (const float*)d_in[19];
  const float* Wc = (const float*)d_in[20];
  const float* bc = (const float*)d_in[21];
  const float* Wsm = (const float*)d_in[22];
  const float* bs = (const float*)d_in[23];
  const float* WpP = (const float*)d_in[24];
  const float* bpP = (const float*)d_in[25];
  const float* WpS = (const float*)d_in[26];
  const float* bpS = (const float*)d_in[27];

  const int NU = in_sizes[0] / 64;
  const int NI = in_sizes[1] / 64;
  const int NR = in_sizes[2];
  const int NL = in_sizes[4];
  const int NMAX = NU > NI ? NU : NI;
  const size_t MAT = (size_t)NMAX * 64;

  float* ws = (float*)d_ws;
  float* B0 = ws + 0 * MAT;  // fs scratch / cheb h_hat
  float* B1 = ws + 1 * MAT;  // fd scratch
  float* B2 = ws + 2 * MAT;  // h1_item -> T1 -> user_social -> h_mS
  float* B3 = ws + 3 * MAT;  // h2_user -> T2 -> h_mP
  float* B4 = ws + 4 * MAT;  // item_infl -> h_uP
  float* B5 = ws + 5 * MAT;  // social_item -> h_uS
  float* B6 = ws + 6 * MAT;  // user_pref -> h_new_P
  float* B7 = ws + 7 * MAT;  // rst -> h_new_S
  // int scratch after 8 float buffers
  int* ip = (int*)(ws + 8 * MAT);
  int* rp_rd = ip;                 // NI+1  (rate grouped by dst=item)
  int* rp_rs = rp_rd + (NI + 1);   // NU+1  (rate grouped by src=user)
  int* rp_ld = rp_rs + (NU + 1);   // NU+1  (link grouped by dst=user)
  int* srt_rd = rp_ld + (NU + 1);  // NR    (rate_src sorted by rate_dst)
  int* srt_rs = srt_rd + NR;       // NR    (rate_dst sorted by rate_src)
  int* srt_ld = srt_rs + NR;       // NL    (link_src sorted by link_dst)
  int* cnt = srt_ld + NL;          // NMAX+1 (sort scratch)
  int* cursor = cnt + (NMAX + 1);  // NMAX
  int* bsum = cursor + NMAX;       // 256
  float* dinv = (float*)(bsum + 256);  // NU

  const int W64 = 64 * 64, B64 = 64;

  // ---- build the 3 CSR groupings (reused by 5 GATs + cheb + indeg) ----
  build_csr(rate_dst, rate_src, NR, NI, rp_rd, srt_rd, cnt, cursor, bsum, stream);
  build_csr(rate_src, rate_dst, NR, NU, rp_rs, srt_rs, cnt, cursor, bsum, stream);
  build_csr(link_dst, link_src, NL, NU, rp_ld, srt_ld, cnt, cursor, bsum, stream);

  // ---- gat0: user -> item over rate edges -> B2 (h1_item, normalized) ----
  run_gat(user_emb, NU, item_emb, NI,
          gat_Wsrc + 0 * W64, gat_bsrc + 0 * B64, gat_Wdst + 0 * W64,
          gat_bdst + 0 * B64, gat_attn + 0 * B64,
          rp_rd, srt_rd, B0, B1, B2, stream);
  // ---- gat1: item -> user (reverse rate) -> B3 (h2_user) ----
  run_gat(item_emb, NI, user_emb, NU,
          gat_Wsrc + 1 * W64, gat_bsrc + 1 * B64, gat_Wdst + 1 * W64,
          gat_bdst + 1 * B64, gat_attn + 1 * B64,
          rp_rs, srt_rs, B0, B1, B3, stream);
  // ---- gat2: h1_item -> user -> B4 (item_infl) ----
  run_gat(B2, NI, user_emb, NU,
          gat_Wsrc + 2 * W64, gat_bsrc + 2 * B64, gat_Wdst + 2 * W64,
          gat_bdst + 2 * B64, gat_attn + 2 * B64,
          rp_rs, srt_rs, B0, B1, B4, stream);
  // ---- gat3: h2_user -> user over link edges -> B5 (social_item) ----
  run_gat(B3, NU, user_emb, NU,
          gat_Wsrc + 3 * W64, gat_bsrc + 3 * B64, gat_Wdst + 3 * W64,
          gat_bdst + 3 * B64, gat_attn + 3 * B64,
          rp_ld, srt_ld, B0, B1, B5, stream);
  // ---- user_pref = [item_infl, social_item] @ W_out + b_out -> B6 ----
  gemm_multi_k<2><<<GEMM_BLOCKS, 256, 0, stream>>>(B4, B5, nullptr, W_out, b_out, B6, NU);

  // ---- ChebConv(k=3) on link graph ----
  dinv_k<<<(NU + 255) / 256, 256, 0, stream>>>(rp_ld, dinv, NU);
  const int TOT = NU * 64;
  ahat_csr_k<<<EDGE_BLOCKS, 256, 0, stream>>>(user_emb, dinv, rp_ld, srt_ld, B0, NU);
  t1_k<<<EDGE_BLOCKS, 256, 0, stream>>>((const float4*)B0, (const float4*)user_emb,
                                        lam, (float4*)B2, TOT / 4);
  ahat_csr_k<<<EDGE_BLOCKS, 256, 0, stream>>>(B2, dinv, rp_ld, srt_ld, B0, NU);
  t2_k<<<EDGE_BLOCKS, 256, 0, stream>>>((const float4*)B0, (const float4*)B2,
                                        (const float4*)user_emb, lam, (float4*)B3, TOT / 4);
  // rst = T0@W0 + T1@W1 + T2@W2 + b -> B7
  gemm_multi_k<3><<<GEMM_BLOCKS, 256, 0, stream>>>(user_emb, B2, B3, cheb_W, cheb_b, B7, NU);

  // ---- gat4: rst -> rst over link edges -> B2 (user_social) ----
  run_gat(B7, NU, B7, NU,
          gat_Wsrc + 4 * W64, gat_bsrc + 4 * B64, gat_Wdst + 4 * W64,
          gat_bdst + 4 * B64, gat_attn + 4 * B64,
          rp_ld, srt_ld, B0, B1, B2, stream);

  // ---- mutualistic ----
  gemm_multi_k<2><<<GEMM_BLOCKS, 256, 0, stream>>>(B6, user_emb, nullptr, Wc, bc, B4, NU);  // h_uP
  gemm_multi_k<2><<<GEMM_BLOCKS, 256, 0, stream>>>(B2, user_emb, nullptr, Wsm, bs, B5, NU); // h_uS
  mut_k<<<(NU + 3) / 4, 256, 0, stream>>>(B4, B5, B3, B2, NU);  // mP->B3, mS->B2
  gemm_multi_k<2><<<GEMM_BLOCKS, 256, 0, stream>>>(B3, B4, nullptr, WpP, bpP, B6, NU);  // h_new_P
  gemm_multi_k<2><<<GEMM_BLOCKS, 256, 0, stream>>>(B2, B5, nullptr, WpS, bpS, B7, NU);  // h_new_S

  // ---- predictors ----
  float* out = (float*)d_out;
  dot_k<<<EDGE_BLOCKS, 256, 0, stream>>>(B6, item_emb, rate_src, rate_dst, out, NR);
  dot_k<<<EDGE_BLOCKS, 256, 0, stream>>>(B6, item_emb, neg_rate_src, neg_rate_dst, out + NR, NR);
  dot_k<<<EDGE_BLOCKS, 256, 0, stream>>>(B7, user_emb, link_src, link_dst, out + 2 * (size_t)NR, NL);
  dot_k<<<EDGE_BLOCKS, 256, 0, stream>>>(B7, user_emb, neg_link_src, neg_link_dst, out + 2 * (size_t)NR + NL, NL);
}